// Round 1
// baseline (383.210 us; speedup 1.0000x reference)
//
#include <hip/hip_runtime.h>
#include <hip/hip_bf16.h>
#include <cstdint>
#include <cstddef>

typedef __bf16 bf16_t;
typedef __bf16 bf16x8 __attribute__((ext_vector_type(8)));
typedef __bf16 bf16x4 __attribute__((ext_vector_type(4)));
typedef float  f32x4  __attribute__((ext_vector_type(4)));
typedef unsigned int   u32x4 __attribute__((ext_vector_type(4)));
typedef unsigned short u16x8 __attribute__((ext_vector_type(8)));

#define DEVI static __device__ __forceinline__

#define EMB    1024
#define NHEAD  16
#define HDIM   64
#define SEQ    2048
#define NBATCH 4
#define MTOT   8192   // B*N

// logits = (q.k)*scale/K_TEMP + hint ; log2 domain: (q.k)*CQK2 + hint*LOG2E
// scale/K_TEMP = 0.125*PHI^2/4 = PHI^2/32
constexpr double PHI2   = 2.618033988749895;
constexpr double LOG2E  = 1.4426950408889634;
constexpr float  CQK2f  = (float)(PHI2 / 32.0 * LOG2E);
constexpr float  LOG2Ef = (float)LOG2E;

DEVI f32x4 MFMA(bf16x8 a, bf16x8 b, f32x4 c) {
  return __builtin_amdgcn_mfma_f32_16x16x32_bf16(a, b, c, 0, 0, 0);
}
DEVI unsigned short bfbits(float v) {
  bf16_t b = (bf16_t)v;
  return __builtin_bit_cast(unsigned short, b);
}

// ---------------- prepass: x fp32 -> bf16 ----------------
__global__ __launch_bounds__(256) void k_cvt_x(const float* __restrict__ x,
                                               bf16_t* __restrict__ xb) {
  int i = (blockIdx.x * 256 + threadIdx.x) * 4;
  f32x4 v = *(const f32x4*)(x + i);
  bf16x4 o;
  o[0] = (bf16_t)v[0]; o[1] = (bf16_t)v[1];
  o[2] = (bf16_t)v[2]; o[3] = (bf16_t)v[3];
  *(bf16x4*)(xb + i) = o;
}

// ---------- prepass: W (K,N) fp32 -> Wt (N,K) bf16 (tiled transpose) ----------
__global__ __launch_bounds__(256) void k_wt(const float* __restrict__ W,
                                            bf16_t* __restrict__ Wt) {
  __shared__ float tile[32][33];
  const int n0 = blockIdx.x * 32, k0 = blockIdx.y * 32;
  const int tx = threadIdx.x, ty = threadIdx.y;  // block (32,8)
#pragma unroll
  for (int i = 0; i < 32; i += 8)
    tile[ty + i][tx] = W[(size_t)(k0 + ty + i) * EMB + n0 + tx];
  __syncthreads();
#pragma unroll
  for (int i = 0; i < 32; i += 8)
    Wt[(size_t)(n0 + ty + i) * EMB + k0 + tx] = (bf16_t)tile[tx][ty + i];
}

// ---------------- GEMM: C[M,N] = A[M,K] @ Bt[N,K]^T  (bf16, fp32 acc) --------
// 128x128 tile, BK=32, 256 threads (2x2 waves, each 64x64), m97 structure.
// EPI 0: scatter to Q/K/V (B,H,N,64) bf16 + bias ; EPI 1: fp32 C + bias.
template <int EPI>
__global__ __launch_bounds__(256) void k_gemm(
    const bf16_t* __restrict__ A, const bf16_t* __restrict__ Bt, int nbt,
    bf16_t* __restrict__ Qb, bf16_t* __restrict__ Kb, bf16_t* __restrict__ Vb,
    const float* __restrict__ bz0, const float* __restrict__ bz1,
    const float* __restrict__ bz2, float* __restrict__ Co) {
  constexpr int K = 1024;
  __shared__ alignas(16) char sA[8192];  // [128][32] bf16
  __shared__ alignas(16) char sB[8192];
  const int t = threadIdx.x, lane = t & 63, wid = t >> 6;
  const int mb = blockIdx.x / nbt, nb = blockIdx.x % nbt;
  const int wr = wid >> 1, wc = wid & 1;
  const int l15 = lane & 15, lg = lane >> 4;
  f32x4 acc[4][4] = {};
  const int arow = t >> 2, aseg = t & 3;
  const bf16_t* gA = A + (size_t)(mb * 128 + arow) * K + aseg * 8;
  const bf16_t* gB = Bt + (size_t)(nb * 128 + arow) * K + aseg * 8;

  for (int kt = 0; kt < K; kt += 32) {
    u32x4 a0 = *(const u32x4*)(gA + kt);
    u32x4 a1 = *(const u32x4*)(gA + kt + 64 * K);
    u32x4 b0 = *(const u32x4*)(gB + kt);
    u32x4 b1 = *(const u32x4*)(gB + kt + 64 * K);
    __syncthreads();
    *(u32x4*)(sA + t * 16)        = a0;
    *(u32x4*)(sA + 4096 + t * 16) = a1;
    *(u32x4*)(sB + t * 16)        = b0;
    *(u32x4*)(sB + 4096 + t * 16) = b1;
    __syncthreads();
    bf16x8 af[4], bfr[4];
#pragma unroll
    for (int mi = 0; mi < 4; mi++)
      af[mi] = *(const bf16x8*)(sA + ((wr * 64 + mi * 16 + l15) * 32 + lg * 8) * 2);
#pragma unroll
    for (int ni = 0; ni < 4; ni++)
      bfr[ni] = *(const bf16x8*)(sB + ((wc * 64 + ni * 16 + l15) * 32 + lg * 8) * 2);
#pragma unroll
    for (int mi = 0; mi < 4; mi++)
#pragma unroll
      for (int ni = 0; ni < 4; ni++)
        acc[mi][ni] = MFMA(af[mi], bfr[ni], acc[mi][ni]);
  }

#pragma unroll
  for (int mi = 0; mi < 4; mi++) {
#pragma unroll
    for (int ni = 0; ni < 4; ni++) {
      const int n = nb * 128 + wc * 64 + ni * 16 + l15;
#pragma unroll
      for (int r = 0; r < 4; r++) {
        const int m = mb * 128 + wr * 64 + mi * 16 + lg * 4 + r;
        float v = acc[mi][ni][r];
        if constexpr (EPI == 0) {
          const int proj = n >> 10, c = n & 1023;
          const float* bp = proj == 0 ? bz0 : (proj == 1 ? bz1 : bz2);
          bf16_t* dst = proj == 0 ? Qb : (proj == 1 ? Kb : Vb);
          v += bp[c];
          const int bb = m >> 11, nr = m & 2047, hh = c >> 6, hd = c & 63;
          dst[(size_t)((bb * NHEAD + hh) * SEQ + nr) * HDIM + hd] = (bf16_t)v;
        } else {
          v += bz0[n];
          Co[(size_t)m * EMB + n] = v;
        }
      }
    }
  }
}

// --------------- flash attention: 1 block per (b,h,64 q-rows) ----------------
__global__ __launch_bounds__(256) void k_attn(
    const bf16_t* __restrict__ Qb, const bf16_t* __restrict__ Kb,
    const bf16_t* __restrict__ Vb, const float* __restrict__ hint,
    bf16_t* __restrict__ Ob) {
  __shared__ alignas(16) char sK[8192];  // [key][hd] XOR-swizzled
  __shared__ alignas(16) char sV[8192];  // [hd][key] dual-XOR swizzled (V^T)
  __shared__ alignas(16) char sP[8192];  // per-wave [16][64] XOR-swizzled
  const int t = threadIdx.x, lane = t & 63, wid = t >> 6;
  const int bh = blockIdx.x >> 5, qb = blockIdx.x & 31;
  const int b = bh >> 4, h = bh & 15;
  const int l15 = lane & 15, lg = lane >> 4;

  // Q fragments straight from global (16 rows per wave)
  const bf16_t* Qg = Qb + ((size_t)bh * SEQ + qb * 64 + wid * 16) * HDIM;
  const bf16x8 aq0 = *(const bf16x8*)(Qg + l15 * HDIM + lg * 8);
  const bf16x8 aq1 = *(const bf16x8*)(Qg + l15 * HDIM + 32 + lg * 8);

  const bf16_t* Kg = Kb + (size_t)bh * SEQ * HDIM;
  const bf16_t* Vg = Vb + (size_t)bh * SEQ * HDIM;
  const float* hb = hint + b * SEQ;

  float mrow[4], lrow[4];
  f32x4 oc[4];
#pragma unroll
  for (int r = 0; r < 4; r++) { mrow[r] = -1e30f; lrow[r] = 0.f; }
#pragma unroll
  for (int cb = 0; cb < 4; cb++) oc[cb] = (f32x4){0.f, 0.f, 0.f, 0.f};

  const int srow = t >> 3, sseg = t & 7;

  for (int kt = 0; kt < 32; ++kt) {
    const bf16_t* kg = Kg + ((size_t)kt * 64 + srow) * HDIM + sseg * 8;
    const bf16_t* vg = Vg + ((size_t)kt * 64 + srow) * HDIM + sseg * 8;
    u32x4 k0 = *(const u32x4*)(kg);
    u32x4 k1 = *(const u32x4*)(kg + 32 * HDIM);
    u16x8 v0 = *(const u16x8*)(vg);
    u16x8 v1 = *(const u16x8*)(vg + 32 * HDIM);
    __syncthreads();
    {
      const int key0 = srow, key1 = srow + 32;
      *(u32x4*)(sK + key0 * 128 + ((sseg * 16) ^ ((key0 & 7) << 4))) = k0;
      *(u32x4*)(sK + key1 * 128 + ((sseg * 16) ^ ((key1 & 7) << 4))) = k1;
#pragma unroll
      for (int e = 0; e < 8; e++) {  // transpose V into sV[hd][key]
        const int hd = sseg * 8 + e;
        const int swz = ((e ^ sseg) & 7) << 4;  // (hd&7)^(hd>>3)
        *(unsigned short*)(sV + hd * 128 + ((key0 * 2) ^ swz)) = v0[e];
        *(unsigned short*)(sV + hd * 128 + ((key1 * 2) ^ swz)) = v1[e];
      }
    }
    __syncthreads();

    // S = Q @ K^T  (per wave: 16 q-rows x 64 keys)
    f32x4 sc[4];
#pragma unroll
    for (int cb = 0; cb < 4; cb++) {
      const int krow = cb * 16 + l15;
      const int rs = (krow & 7) << 4;
      bf16x8 bk0 = *(const bf16x8*)(sK + krow * 128 + ((lg * 16) ^ rs));
      bf16x8 bk1 = *(const bf16x8*)(sK + krow * 128 + ((64 + lg * 16) ^ rs));
      f32x4 s = (f32x4){0.f, 0.f, 0.f, 0.f};
      s = MFMA(aq0, bk0, s);
      s = MFMA(aq1, bk1, s);
      sc[cb] = s;
    }

    // log2-domain logits + online softmax
    float p[4][4], hv[4];
#pragma unroll
    for (int cb = 0; cb < 4; cb++) hv[cb] = hb[kt * 64 + cb * 16 + l15] * LOG2Ef;
#pragma unroll
    for (int cb = 0; cb < 4; cb++)
#pragma unroll
      for (int r = 0; r < 4; r++) p[cb][r] = sc[cb][r] * CQK2f + hv[cb];
#pragma unroll
    for (int r = 0; r < 4; r++) {
      float mx = fmaxf(fmaxf(p[0][r], p[1][r]), fmaxf(p[2][r], p[3][r]));
      mx = fmaxf(mx, __shfl_xor(mx, 1, 16));
      mx = fmaxf(mx, __shfl_xor(mx, 2, 16));
      mx = fmaxf(mx, __shfl_xor(mx, 4, 16));
      mx = fmaxf(mx, __shfl_xor(mx, 8, 16));
      const float mn = fmaxf(mrow[r], mx);
      const float corr = exp2f(mrow[r] - mn);
      mrow[r] = mn;
      float ps = 0.f;
#pragma unroll
      for (int cb = 0; cb < 4; cb++) {
        float e = exp2f(p[cb][r] - mn);
        p[cb][r] = e;
        ps += e;
      }
      ps += __shfl_xor(ps, 1, 16);
      ps += __shfl_xor(ps, 2, 16);
      ps += __shfl_xor(ps, 4, 16);
      ps += __shfl_xor(ps, 8, 16);
      lrow[r] = lrow[r] * corr + ps;
#pragma unroll
      for (int cb = 0; cb < 4; cb++) oc[cb][r] *= corr;
    }

    // P -> per-wave LDS (C-frag layout -> A-frag layout)
#pragma unroll
    for (int cb = 0; cb < 4; cb++)
#pragma unroll
      for (int r = 0; r < 4; r++) {
        const int row = lg * 4 + r, col = cb * 16 + l15;
        *(unsigned short*)(sP + wid * 2048 + row * 128 +
                           ((col * 2) ^ ((row & 7) << 4))) = bfbits(p[cb][r]);
      }
    __syncthreads();

    // O += P @ V  (V read transposed from sV)
#pragma unroll
    for (int kc = 0; kc < 2; kc++) {
      bf16x8 pa = *(const bf16x8*)(sP + wid * 2048 + l15 * 128 +
                                   ((kc * 64 + lg * 16) ^ ((l15 & 7) << 4)));
#pragma unroll
      for (int cb = 0; cb < 4; cb++) {
        const int hd = cb * 16 + l15;
        const int swz = (((hd & 7) ^ (hd >> 3)) & 7) << 4;
        bf16x8 bv = *(const bf16x8*)(sV + hd * 128 + ((kc * 64 + lg * 16) ^ swz));
        oc[cb] = MFMA(pa, bv, oc[cb]);
      }
    }
  }

  // epilogue: normalize, write (B,N,EMB) bf16
#pragma unroll
  for (int cb = 0; cb < 4; cb++) {
#pragma unroll
    for (int r = 0; r < 4; r++) {
      const int row = qb * 64 + wid * 16 + lg * 4 + r;
      const float v = oc[cb][r] / lrow[r];
      Ob[((size_t)b * SEQ + row) * EMB + h * HDIM + cb * 16 + l15] = (bf16_t)v;
    }
  }
}

// ------------------------------- launcher ------------------------------------
extern "C" void kernel_launch(void* const* d_in, const int* in_sizes, int n_in,
                              void* d_out, int out_size, void* d_ws,
                              size_t ws_size, hipStream_t stream) {
  const float* x    = (const float*)d_in[0];
  const float* hint = (const float*)d_in[1];
  const float* Wq   = (const float*)d_in[2];
  const float* bq   = (const float*)d_in[3];
  const float* Wk   = (const float*)d_in[4];
  const float* bk   = (const float*)d_in[5];
  const float* Wv   = (const float*)d_in[6];
  const float* bv   = (const float*)d_in[7];
  const float* Wo   = (const float*)d_in[8];
  const float* bo   = (const float*)d_in[9];
  float* out = (float*)d_out;

  char* w = (char*)d_ws;
  const size_t SZ_XB = (size_t)MTOT * EMB * 2;        // 16 MB
  const size_t SZ_WQKVT = (size_t)3 * EMB * EMB * 2;  // 6 MB
  const size_t SZ_WOT = (size_t)EMB * EMB * 2;        // 2 MB
  const size_t SZ_QKV = (size_t)MTOT * EMB * 2;       // 16 MB each
  bf16_t* xb    = (bf16_t*)(w);
  bf16_t* wqkvt = (bf16_t*)(w + SZ_XB);
  bf16_t* wot   = (bf16_t*)(w + SZ_XB + SZ_WQKVT);
  bf16_t* qb    = (bf16_t*)(w + SZ_XB + SZ_WQKVT + SZ_WOT);
  bf16_t* kb    = (bf16_t*)(w + SZ_XB + SZ_WQKVT + SZ_WOT + SZ_QKV);
  bf16_t* vb    = (bf16_t*)(w + SZ_XB + SZ_WQKVT + SZ_WOT + 2 * SZ_QKV);
  bf16_t* ob    = (bf16_t*)(w + SZ_XB + SZ_WQKVT + SZ_WOT + 3 * SZ_QKV);

  // prepass
  k_cvt_x<<<(MTOT * EMB) / 1024, 256, 0, stream>>>(x, xb);
  dim3 wtg(32, 32), wtb(32, 8);
  k_wt<<<wtg, wtb, 0, stream>>>(Wq, wqkvt);
  k_wt<<<wtg, wtb, 0, stream>>>(Wk, wqkvt + (size_t)EMB * EMB);
  k_wt<<<wtg, wtb, 0, stream>>>(Wv, wqkvt + (size_t)2 * EMB * EMB);
  k_wt<<<wtg, wtb, 0, stream>>>(Wo, wot);

  // QKV projection: (8192 x 3072) = xb @ [Wq|Wk|Wv]
  k_gemm<0><<<64 * 24, 256, 0, stream>>>(xb, wqkvt, 24, qb, kb, vb, bq, bk, bv,
                                         nullptr);
  // attention
  k_attn<<<NBATCH * NHEAD * (SEQ / 64), 256, 0, stream>>>(qb, kb, vb, hint, ob);
  // output projection
  k_gemm<1><<<64 * 8, 256, 0, stream>>>(ob, wot, 8, nullptr, nullptr, nullptr,
                                        bo, nullptr, nullptr, out);
}

// Round 3
// 315.879 us; speedup vs baseline: 1.2132x; 1.2132x over previous
//
#include <hip/hip_runtime.h>
#include <hip/hip_bf16.h>
#include <cstdint>
#include <cstddef>

typedef __bf16 bf16_t;
typedef __bf16 bf16x8 __attribute__((ext_vector_type(8)));
typedef __bf16 bf16x4 __attribute__((ext_vector_type(4)));
typedef float  f32x4  __attribute__((ext_vector_type(4)));
typedef float  f32x16 __attribute__((ext_vector_type(16)));
typedef unsigned int   u32x2 __attribute__((ext_vector_type(2)));
typedef unsigned int   u32x4 __attribute__((ext_vector_type(4)));

#define DEVI static __device__ __forceinline__

#define EMB    1024
#define NHEAD  16
#define HDIM   64
#define SEQ    2048
#define NBATCH 4
#define MTOT   8192   // B*N
#define KVB    64

// logits = (q.k)*scale/K_TEMP + hint ; log2 domain: (q.k)*CQK2 + hint*LOG2E
// scale/K_TEMP = 0.125*PHI^2/4 = PHI^2/32.  CQK2 is folded into Q at GEMM1
// epilogue; hint*LOG2E is folded into the QK^T MFMA accumulator init.
constexpr double PHI2   = 2.618033988749895;
constexpr double LOG2E  = 1.4426950408889634;
constexpr float  CQK2f  = (float)(PHI2 / 32.0 * LOG2E);
constexpr float  LOG2Ef = (float)LOG2E;

DEVI f32x4 MFMA(bf16x8 a, bf16x8 b, f32x4 c) {
  return __builtin_amdgcn_mfma_f32_16x16x32_bf16(a, b, c, 0, 0, 0);
}
DEVI f32x16 MFMA32(bf16x8 a, bf16x8 b, f32x16 c) {
  return __builtin_amdgcn_mfma_f32_32x32x16_bf16(a, b, c, 0, 0, 0);
}
DEVI unsigned short bfbits(float v) {
  bf16_t b = (bf16_t)v;
  return __builtin_bit_cast(unsigned short, b);
}
DEVI unsigned pk2(float lo, float hi) {  // pack 2 f32 -> bf16x2 word
  return ((unsigned)bfbits(hi) << 16) | (unsigned)bfbits(lo);
}

// ---------------- prepass: x fp32 -> bf16 ----------------
__global__ __launch_bounds__(256) void k_cvt_x(const float* __restrict__ x,
                                               bf16_t* __restrict__ xb) {
  int i = (blockIdx.x * 256 + threadIdx.x) * 4;
  f32x4 v = *(const f32x4*)(x + i);
  bf16x4 o;
  o[0] = (bf16_t)v[0]; o[1] = (bf16_t)v[1];
  o[2] = (bf16_t)v[2]; o[3] = (bf16_t)v[3];
  *(bf16x4*)(xb + i) = o;
}

// ---------- prepass: W (K,N) fp32 -> Wt (N,K) bf16 (tiled transpose) ----------
__global__ __launch_bounds__(256) void k_wt(const float* __restrict__ W,
                                            bf16_t* __restrict__ Wt) {
  __shared__ float tile[32][33];
  const int n0 = blockIdx.x * 32, k0 = blockIdx.y * 32;
  const int tx = threadIdx.x, ty = threadIdx.y;  // block (32,8)
#pragma unroll
  for (int i = 0; i < 32; i += 8)
    tile[ty + i][tx] = W[(size_t)(k0 + ty + i) * EMB + n0 + tx];
  __syncthreads();
#pragma unroll
  for (int i = 0; i < 32; i += 8)
    Wt[(size_t)(n0 + ty + i) * EMB + k0 + tx] = (bf16_t)tile[tx][ty + i];
}

// ---------------- GEMM: C[M,N] = A[M,K] @ Bt[N,K]^T  (bf16, fp32 acc) --------
// 128x128 tile, BK=32, 256 threads (2x2 waves, each 64x64), m97 structure.
// EPI 0: scatter Q (scaled by CQK2f, (B,H,N,64)), K ((B,H,N,64)),
//        V transposed ((B,H,64,N)) + biases.
// EPI 1: fp32 C + bias.
template <int EPI>
__global__ __launch_bounds__(256) void k_gemm(
    const bf16_t* __restrict__ A, const bf16_t* __restrict__ Bt, int nbt,
    bf16_t* __restrict__ Qb, bf16_t* __restrict__ Kb, bf16_t* __restrict__ Vb,
    const float* __restrict__ bz0, const float* __restrict__ bz1,
    const float* __restrict__ bz2, float* __restrict__ Co) {
  constexpr int K = 1024;
  __shared__ alignas(16) char sA[8192];  // [128][32] bf16
  __shared__ alignas(16) char sB[8192];
  const int t = threadIdx.x, lane = t & 63, wid = t >> 6;
  const int mb = blockIdx.x / nbt, nb = blockIdx.x % nbt;
  const int wr = wid >> 1, wc = wid & 1;
  const int l15 = lane & 15, lg = lane >> 4;
  f32x4 acc[4][4] = {};
  const int arow = t >> 2, aseg = t & 3;
  const bf16_t* gA = A + (size_t)(mb * 128 + arow) * K + aseg * 8;
  const bf16_t* gB = Bt + (size_t)(nb * 128 + arow) * K + aseg * 8;

  for (int kt = 0; kt < K; kt += 32) {
    u32x4 a0 = *(const u32x4*)(gA + kt);
    u32x4 a1 = *(const u32x4*)(gA + kt + 64 * K);
    u32x4 b0 = *(const u32x4*)(gB + kt);
    u32x4 b1 = *(const u32x4*)(gB + kt + 64 * K);
    __syncthreads();
    *(u32x4*)(sA + t * 16)        = a0;
    *(u32x4*)(sA + 4096 + t * 16) = a1;
    *(u32x4*)(sB + t * 16)        = b0;
    *(u32x4*)(sB + 4096 + t * 16) = b1;
    __syncthreads();
    bf16x8 af[4], bfr[4];
#pragma unroll
    for (int mi = 0; mi < 4; mi++)
      af[mi] = *(const bf16x8*)(sA + ((wr * 64 + mi * 16 + l15) * 32 + lg * 8) * 2);
#pragma unroll
    for (int ni = 0; ni < 4; ni++)
      bfr[ni] = *(const bf16x8*)(sB + ((wc * 64 + ni * 16 + l15) * 32 + lg * 8) * 2);
#pragma unroll
    for (int mi = 0; mi < 4; mi++)
#pragma unroll
      for (int ni = 0; ni < 4; ni++)
        acc[mi][ni] = MFMA(af[mi], bfr[ni], acc[mi][ni]);
  }

#pragma unroll
  for (int mi = 0; mi < 4; mi++) {
#pragma unroll
    for (int ni = 0; ni < 4; ni++) {
      const int n = nb * 128 + wc * 64 + ni * 16 + l15;
#pragma unroll
      for (int r = 0; r < 4; r++) {
        const int m = mb * 128 + wr * 64 + mi * 16 + lg * 4 + r;
        float v = acc[mi][ni][r];
        if constexpr (EPI == 0) {
          const int proj = n >> 10, c = n & 1023;
          const int bb = m >> 11, nr = m & 2047, hh = c >> 6, hd = c & 63;
          if (proj == 0) {
            Qb[(size_t)((bb * NHEAD + hh) * SEQ + nr) * HDIM + hd] =
                (bf16_t)((v + bz0[c]) * CQK2f);
          } else if (proj == 1) {
            Kb[(size_t)((bb * NHEAD + hh) * SEQ + nr) * HDIM + hd] =
                (bf16_t)(v + bz1[c]);
          } else {  // V stored transposed: (B,H,64,N)
            Vb[((size_t)(bb * NHEAD + hh) * HDIM + hd) * SEQ + nr] =
                (bf16_t)(v + bz2[c]);
          }
        } else {
          v += bz0[n];
          Co[(size_t)m * EMB + n] = v;
        }
      }
    }
  }
}

// --------------- flash attention v2: 8 warps, 32x32 MFMA, swapped operands ---
// Block: 512 threads (8 warps), 256 q-rows (32/warp), KV tile = 64 keys.
// S^T = mfma32(K, Q): lane owns q = lane&31 -> softmax fully per-lane +
// one shfl_xor(32).  O^T = mfma32(V^T, P^T): rescale lane-local.
// P^T B-frags are the lane's OWN e-values in natural order kappa(e,hi) =
// (e&3)+8*(e>>2)+4*hi; the V^T A-frag is loaded with the SAME kappa order
// (two b64 LDS reads), so the MFMA contraction pairs correctly regardless
// of the hardware k-mapping (k-permutation cancellation).
__global__ __launch_bounds__(512) void k_attn2(
    const bf16_t* __restrict__ Qb, const bf16_t* __restrict__ Kb,
    const bf16_t* __restrict__ Vt, const float* __restrict__ hint,
    bf16_t* __restrict__ Ob) {
  __shared__ alignas(16) char sK[2][8192];   // [64 key][64 hd] swizzled
  __shared__ alignas(16) char sV[2][8192];   // [64 hd][64 key] swizzled
  __shared__ alignas(16) char sO[32768];     // per-warp 4KB: [32 q][64 hd]
  const int t = threadIdx.x, lane = t & 63, w = t >> 6;
  const int bh = blockIdx.x & 63, qc = blockIdx.x >> 6;  // bh fastest: same-bh
  const int b = bh >> 4, h = bh & 15;                    // blocks -> same XCD
  const int l31 = lane & 31, hi = lane >> 5;
  const int rs = (l31 & 7) << 4;

  // Q B-frags (held in registers, Q pre-scaled by CQK2f in GEMM1)
  bf16x8 qf[4];
  {
    const bf16_t* Qg =
        Qb + ((size_t)bh * SEQ + qc * 256 + w * 32 + l31) * HDIM + hi * 8;
#pragma unroll
    for (int kb = 0; kb < 4; kb++) qf[kb] = *(const bf16x8*)(Qg + kb * 16);
  }

  // staging: thread t covers row srow, 16B segment sseg (same for K and V^T)
  const int srow = t >> 3, sseg = t & 7;
  const bf16_t* Kg =
      Kb + (size_t)bh * SEQ * HDIM + (size_t)srow * HDIM + sseg * 8;
  const bf16_t* Vg =
      Vt + (size_t)bh * HDIM * SEQ + (size_t)srow * SEQ + sseg * 8;
  const int soff = srow * 128 + ((sseg * 16) ^ ((srow & 7) << 4));

  {  // prologue: stage tile 0
    u32x4 k0 = *(const u32x4*)Kg;
    u32x4 v0 = *(const u32x4*)Vg;
    *(u32x4*)(sK[0] + soff) = k0;
    *(u32x4*)(sV[0] + soff) = v0;
  }

  const float* hb = hint + b * SEQ + hi * 4;

  float m_run = -1e30f, l_run = 0.f;
  f32x16 oa0, oa1;
#pragma unroll
  for (int r = 0; r < 16; r++) { oa0[r] = 0.f; oa1[r] = 0.f; }

  for (int kt = 0; kt < 32; ++kt) {
    const int cur = kt & 1;
    u32x4 knx, vnx;
    if (kt < 31) {  // T14: issue next-tile loads before compute
      knx = *(const u32x4*)(Kg + (size_t)(kt + 1) * (KVB * HDIM));
      vnx = *(const u32x4*)(Vg + (kt + 1) * KVB);
    }
    __syncthreads();
    const char* bK = sK[cur];
    const char* bV = sV[cur];

    // S^T accumulators, init = hint[key]*LOG2E (key = crow(r,hi))
    f32x16 s0, s1;
#pragma unroll
    for (int g = 0; g < 4; g++) {
      f32x4 h0 = *(const f32x4*)(hb + kt * 64 + 8 * g);
      f32x4 h1 = *(const f32x4*)(hb + kt * 64 + 32 + 8 * g);
#pragma unroll
      for (int j = 0; j < 4; j++) {
        s0[4 * g + j] = h0[j] * LOG2Ef;
        s1[4 * g + j] = h1[j] * LOG2Ef;
      }
    }
    // QK^T (swapped): A = K rows, B = Q  (same consecutive-k order both sides)
#pragma unroll
    for (int kb = 0; kb < 4; kb++) {
      const int co = (kb * 32 + hi * 16) ^ rs;
      bf16x8 ka0 = *(const bf16x8*)(bK + l31 * 128 + co);
      bf16x8 ka1 = *(const bf16x8*)(bK + (32 + l31) * 128 + co);
      s0 = MFMA32(ka0, qf[kb], s0);
      s1 = MFMA32(ka1, qf[kb], s1);
    }

    // online softmax: per-lane (one q-row), 31 fmax + 1 shfl_xor(32)
    float pm = s0[0];
#pragma unroll
    for (int r = 1; r < 16; r++) pm = fmaxf(pm, s0[r]);
#pragma unroll
    for (int r = 0; r < 16; r++) pm = fmaxf(pm, s1[r]);
    pm = fmaxf(pm, __shfl_xor(pm, 32));
    const float mn = fmaxf(m_run, pm);
    const float corr = __builtin_amdgcn_exp2f(m_run - mn);
    m_run = mn;
    float e0[16], e1[16];
    float ps0 = 0.f, ps1 = 0.f, ps2 = 0.f, ps3 = 0.f;
#pragma unroll
    for (int r = 0; r < 16; r += 4) {
      e0[r + 0] = __builtin_amdgcn_exp2f(s0[r + 0] - mn); ps0 += e0[r + 0];
      e0[r + 1] = __builtin_amdgcn_exp2f(s0[r + 1] - mn); ps1 += e0[r + 1];
      e0[r + 2] = __builtin_amdgcn_exp2f(s0[r + 2] - mn); ps2 += e0[r + 2];
      e0[r + 3] = __builtin_amdgcn_exp2f(s0[r + 3] - mn); ps3 += e0[r + 3];
    }
#pragma unroll
    for (int r = 0; r < 16; r += 4) {
      e1[r + 0] = __builtin_amdgcn_exp2f(s1[r + 0] - mn); ps0 += e1[r + 0];
      e1[r + 1] = __builtin_amdgcn_exp2f(s1[r + 1] - mn); ps1 += e1[r + 1];
      e1[r + 2] = __builtin_amdgcn_exp2f(s1[r + 2] - mn); ps2 += e1[r + 2];
      e1[r + 3] = __builtin_amdgcn_exp2f(s1[r + 3] - mn); ps3 += e1[r + 3];
    }
    float ps = (ps0 + ps1) + (ps2 + ps3);
    ps += __shfl_xor(ps, 32);
    l_run = l_run * corr + ps;
#pragma unroll
    for (int r = 0; r < 16; r++) { oa0[r] *= corr; oa1[r] *= corr; }

    // PV (swapped): O^T += V^T @ P^T.
    // B (P^T): lane's own e-values, natural order kappa(e,hi).
    // A (V^T): rows l31 / 32+l31, keys loaded in the SAME kappa order:
    //   elems 0-3 = keys KS*16+4*hi+0..3, elems 4-7 = keys KS*16+8+4*hi+0..3.
#define PVSTEP(EARR, KS)                                                      \
    {                                                                         \
      constexpr int rb = ((KS) & 1) * 8;                                      \
      u32x4 pw;                                                               \
      pw[0] = pk2(EARR[rb + 0], EARR[rb + 1]);                                \
      pw[1] = pk2(EARR[rb + 2], EARR[rb + 3]);                                \
      pw[2] = pk2(EARR[rb + 4], EARR[rb + 5]);                                \
      pw[3] = pk2(EARR[rb + 6], EARR[rb + 7]);                                \
      bf16x8 pf = __builtin_bit_cast(bf16x8, pw);                             \
      const int c0 = ((KS) * 32 + 8 * hi) ^ rs;                               \
      const int c1 = ((KS) * 32 + 16 + 8 * hi) ^ rs;                          \
      u32x2 a0l = *(const u32x2*)(bV + l31 * 128 + c0);                       \
      u32x2 a0h = *(const u32x2*)(bV + l31 * 128 + c1);                       \
      u32x2 a1l = *(const u32x2*)(bV + (32 + l31) * 128 + c0);                \
      u32x2 a1h = *(const u32x2*)(bV + (32 + l31) * 128 + c1);                \
      u32x4 w0; w0[0] = a0l[0]; w0[1] = a0l[1]; w0[2] = a0h[0]; w0[3] = a0h[1];\
      u32x4 w1; w1[0] = a1l[0]; w1[1] = a1l[1]; w1[2] = a1h[0]; w1[3] = a1h[1];\
      oa0 = MFMA32(__builtin_bit_cast(bf16x8, w0), pf, oa0);                  \
      oa1 = MFMA32(__builtin_bit_cast(bf16x8, w1), pf, oa1);                  \
    }
    PVSTEP(e0, 0)
    PVSTEP(e0, 1)
    PVSTEP(e1, 2)
    PVSTEP(e1, 3)
#undef PVSTEP

    if (kt < 31) {  // write next tile into other buffer
      *(u32x4*)(sK[cur ^ 1] + soff) = knx;
      *(u32x4*)(sV[cur ^ 1] + soff) = vnx;
    }
  }

  // epilogue: normalize, per-warp LDS transpose O^T -> O, vector store
  const float inv = __builtin_amdgcn_rcpf(l_run);
  char* so = sO + w * 4096;
#pragma unroll
  for (int g = 0; g < 4; g++) {
    {
      u32x2 wv;
      wv[0] = pk2(oa0[4 * g + 0] * inv, oa0[4 * g + 1] * inv);
      wv[1] = pk2(oa0[4 * g + 2] * inv, oa0[4 * g + 3] * inv);
      const int colb = 16 * g + 8 * hi;  // hd = 8g+4hi, bytes
      *(u32x2*)(so + l31 * 128 + (colb ^ rs)) = wv;
    }
    {
      u32x2 wv;
      wv[0] = pk2(oa1[4 * g + 0] * inv, oa1[4 * g + 1] * inv);
      wv[1] = pk2(oa1[4 * g + 2] * inv, oa1[4 * g + 3] * inv);
      const int colb = 64 + 16 * g + 8 * hi;
      *(u32x2*)(so + l31 * 128 + (colb ^ rs)) = wv;
    }
  }
  // readback rows (same warp produced them; compiler orders via lgkmcnt)
  const int row = lane >> 1, halfq = lane & 1;
  const int rs2 = (row & 7) << 4;
  bf16_t* od = Ob + ((size_t)b * SEQ + qc * 256 + w * 32 + row) * EMB +
               h * HDIM + halfq * 32;
#pragma unroll
  for (int s2 = 0; s2 < 4; s2++) {
    u32x4 d = *(const u32x4*)(so + row * 128 + ((halfq * 64 + s2 * 16) ^ rs2));
    *(u32x4*)(od + s2 * 8) = d;
  }
}

// ------------------------------- launcher ------------------------------------
extern "C" void kernel_launch(void* const* d_in, const int* in_sizes, int n_in,
                              void* d_out, int out_size, void* d_ws,
                              size_t ws_size, hipStream_t stream) {
  const float* x    = (const float*)d_in[0];
  const float* hint = (const float*)d_in[1];
  const float* Wq   = (const float*)d_in[2];
  const float* bq   = (const float*)d_in[3];
  const float* Wk   = (const float*)d_in[4];
  const float* bk   = (const float*)d_in[5];
  const float* Wv   = (const float*)d_in[6];
  const float* bv   = (const float*)d_in[7];
  const float* Wo   = (const float*)d_in[8];
  const float* bo   = (const float*)d_in[9];
  float* out = (float*)d_out;

  char* w = (char*)d_ws;
  const size_t MB = 1024 * 1024;
  bf16_t* xb    = (bf16_t*)(w);            // 16 MB
  bf16_t* wqkvt = (bf16_t*)(w + 16 * MB);  // 6 MB
  bf16_t* wot   = (bf16_t*)(w + 22 * MB);  // 2 MB
  bf16_t* qb    = (bf16_t*)(w + 24 * MB);  // 16 MB (B,H,N,64), pre-scaled
  bf16_t* kb    = (bf16_t*)(w + 40 * MB);  // 16 MB (B,H,N,64)
  bf16_t* vt    = (bf16_t*)(w + 56 * MB);  // 16 MB (B,H,64,N) transposed
  bf16_t* ob    = (bf16_t*)(w + 72 * MB);  // 16 MB (B,N,EMB)

  // prepass
  k_cvt_x<<<(MTOT * EMB) / 1024, 256, 0, stream>>>(x, xb);
  dim3 wtg(32, 32), wtb(32, 8);
  k_wt<<<wtg, wtb, 0, stream>>>(Wq, wqkvt);
  k_wt<<<wtg, wtb, 0, stream>>>(Wk, wqkvt + (size_t)EMB * EMB);
  k_wt<<<wtg, wtb, 0, stream>>>(Wv, wqkvt + (size_t)2 * EMB * EMB);
  k_wt<<<wtg, wtb, 0, stream>>>(Wo, wot);

  // QKV projection: (8192 x 3072) = xb @ [Wq|Wk|Wv]
  k_gemm<0><<<64 * 24, 256, 0, stream>>>(xb, wqkvt, 24, qb, kb, vt, bq, bk, bv,
                                         nullptr);
  // attention: 512 blocks (8 q-chunks x 64 bh), 512 threads
  k_attn2<<<512, 512, 0, stream>>>(qb, kb, vt, hint, ob);
  // output projection
  k_gemm<1><<<64 * 8, 256, 0, stream>>>(ob, wot, 8, nullptr, nullptr, nullptr,
                                        bo, nullptr, nullptr, out);
}

// Round 4
// 273.041 us; speedup vs baseline: 1.4035x; 1.1569x over previous
//
#include <hip/hip_runtime.h>
#include <hip/hip_bf16.h>
#include <cstdint>
#include <cstddef>

typedef __bf16 bf16_t;
typedef __bf16 bf16x8 __attribute__((ext_vector_type(8)));
typedef __bf16 bf16x4 __attribute__((ext_vector_type(4)));
typedef float  f32x4  __attribute__((ext_vector_type(4)));
typedef float  f32x16 __attribute__((ext_vector_type(16)));
typedef unsigned int   u32x2 __attribute__((ext_vector_type(2)));
typedef unsigned int   u32x4 __attribute__((ext_vector_type(4)));

#define DEVI static __device__ __forceinline__

#define EMB    1024
#define NHEAD  16
#define HDIM   64
#define SEQ    2048
#define NBATCH 4
#define MTOT   8192   // B*N
#define KVB    64

// logits = (q.k)*scale/K_TEMP + hint ; log2 domain: (q.k)*CQK2 + hint*LOG2E
// scale/K_TEMP = 0.125*PHI^2/4 = PHI^2/32.  CQK2 is folded into Q at GEMM1
// epilogue; hint*LOG2E is folded into the QK^T MFMA accumulator init.
constexpr double PHI2   = 2.618033988749895;
constexpr double LOG2E  = 1.4426950408889634;
constexpr float  CQK2f  = (float)(PHI2 / 32.0 * LOG2E);
constexpr float  LOG2Ef = (float)LOG2E;

DEVI f32x4 MFMA(bf16x8 a, bf16x8 b, f32x4 c) {
  return __builtin_amdgcn_mfma_f32_16x16x32_bf16(a, b, c, 0, 0, 0);
}
DEVI f32x16 MFMA32(bf16x8 a, bf16x8 b, f32x16 c) {
  return __builtin_amdgcn_mfma_f32_32x32x16_bf16(a, b, c, 0, 0, 0);
}
DEVI unsigned short bfbits(float v) {
  bf16_t b = (bf16_t)v;
  return __builtin_bit_cast(unsigned short, b);
}
DEVI unsigned pk2(float lo, float hi) {  // pack 2 f32 -> bf16x2 word
  return ((unsigned)bfbits(hi) << 16) | (unsigned)bfbits(lo);
}
// async global -> LDS, 16B per lane (wave-uniform base + lane*16; we pass the
// per-lane contiguous pointer, lane 0's value is the wave base)
DEVI void gload16(const void* g, void* l) {
  __builtin_amdgcn_global_load_lds(
      (const __attribute__((address_space(1))) unsigned int*)g,
      (__attribute__((address_space(3))) unsigned int*)l, 16, 0, 0);
}

// ---------------- prepass: x fp32 -> bf16 ----------------
__global__ __launch_bounds__(256) void k_cvt_x(const float* __restrict__ x,
                                               bf16_t* __restrict__ xb) {
  int i = (blockIdx.x * 256 + threadIdx.x) * 4;
  f32x4 v = *(const f32x4*)(x + i);
  bf16x4 o;
  o[0] = (bf16_t)v[0]; o[1] = (bf16_t)v[1];
  o[2] = (bf16_t)v[2]; o[3] = (bf16_t)v[3];
  *(bf16x4*)(xb + i) = o;
}

// ---------- prepass: W (K,N) fp32 -> Wt (N,K) bf16 (tiled transpose) ----------
__global__ __launch_bounds__(256) void k_wt(const float* __restrict__ W,
                                            bf16_t* __restrict__ Wt) {
  __shared__ float tile[32][33];
  const int n0 = blockIdx.x * 32, k0 = blockIdx.y * 32;
  const int tx = threadIdx.x, ty = threadIdx.y;  // block (32,8)
#pragma unroll
  for (int i = 0; i < 32; i += 8)
    tile[ty + i][tx] = W[(size_t)(k0 + ty + i) * EMB + n0 + tx];
  __syncthreads();
#pragma unroll
  for (int i = 0; i < 32; i += 8)
    Wt[(size_t)(n0 + ty + i) * EMB + k0 + tx] = (bf16_t)tile[tx][ty + i];
}

// ---------------- GEMM: C[M,N] = A[M,K] @ Bt[N,K]^T  (bf16, fp32 acc) --------
// 128x128 tile, BK=32, 256 threads (2x2 waves, each 64x64), m97 structure
// with global_load_lds width-16 staging (linear LDS layout, t*16).
// EPI 0: scatter Q (scaled by CQK2f, (B,H,N,64)), K ((B,H,N,64)),
//        V transposed ((B,H,64,N)) + biases.
// EPI 1: fp32 C + bias.
template <int EPI>
__global__ __launch_bounds__(256) void k_gemm(
    const bf16_t* __restrict__ A, const bf16_t* __restrict__ Bt, int nbt,
    bf16_t* __restrict__ Qb, bf16_t* __restrict__ Kb, bf16_t* __restrict__ Vb,
    const float* __restrict__ bz0, const float* __restrict__ bz1,
    const float* __restrict__ bz2, float* __restrict__ Co) {
  constexpr int K = 1024;
  __shared__ alignas(16) char sA[8192];  // [128][32] bf16
  __shared__ alignas(16) char sB[8192];
  const int t = threadIdx.x, lane = t & 63, wid = t >> 6;
  const int mb = blockIdx.x / nbt, nb = blockIdx.x % nbt;
  const int wr = wid >> 1, wc = wid & 1;
  const int l15 = lane & 15, lg = lane >> 4;
  f32x4 acc[4][4] = {};
  const int arow = t >> 2, aseg = t & 3;
  const bf16_t* gA = A + (size_t)(mb * 128 + arow) * K + aseg * 8;
  const bf16_t* gB = Bt + (size_t)(nb * 128 + arow) * K + aseg * 8;

  for (int kt = 0; kt < K; kt += 32) {
    gload16(gA + kt,          sA + t * 16);
    gload16(gA + kt + 64 * K, sA + 4096 + t * 16);
    gload16(gB + kt,          sB + t * 16);
    gload16(gB + kt + 64 * K, sB + 4096 + t * 16);
    __syncthreads();  // drains vmcnt -> LDS tiles ready
    bf16x8 af[4], bfr[4];
#pragma unroll
    for (int mi = 0; mi < 4; mi++)
      af[mi] = *(const bf16x8*)(sA + ((wr * 64 + mi * 16 + l15) * 32 + lg * 8) * 2);
#pragma unroll
    for (int ni = 0; ni < 4; ni++)
      bfr[ni] = *(const bf16x8*)(sB + ((wc * 64 + ni * 16 + l15) * 32 + lg * 8) * 2);
#pragma unroll
    for (int mi = 0; mi < 4; mi++)
#pragma unroll
      for (int ni = 0; ni < 4; ni++)
        acc[mi][ni] = MFMA(af[mi], bfr[ni], acc[mi][ni]);
    __syncthreads();  // frags consumed before next iter overwrites
  }

#pragma unroll
  for (int mi = 0; mi < 4; mi++) {
#pragma unroll
    for (int ni = 0; ni < 4; ni++) {
      const int n = nb * 128 + wc * 64 + ni * 16 + l15;
#pragma unroll
      for (int r = 0; r < 4; r++) {
        const int m = mb * 128 + wr * 64 + mi * 16 + lg * 4 + r;
        float v = acc[mi][ni][r];
        if constexpr (EPI == 0) {
          const int proj = n >> 10, c = n & 1023;
          const int bb = m >> 11, nr = m & 2047, hh = c >> 6, hd = c & 63;
          if (proj == 0) {
            Qb[(size_t)((bb * NHEAD + hh) * SEQ + nr) * HDIM + hd] =
                (bf16_t)((v + bz0[c]) * CQK2f);
          } else if (proj == 1) {
            Kb[(size_t)((bb * NHEAD + hh) * SEQ + nr) * HDIM + hd] =
                (bf16_t)(v + bz1[c]);
          } else {  // V stored transposed: (B,H,64,N)
            Vb[((size_t)(bb * NHEAD + hh) * HDIM + hd) * SEQ + nr] =
                (bf16_t)(v + bz2[c]);
          }
        } else {
          v += bz0[n];
          Co[(size_t)m * EMB + n] = v;
        }
      }
    }
  }
}

// --------------- flash attention v2: 8 warps, 32x32 MFMA, swapped operands ---
// Block: 512 threads (8 warps), 256 q-rows (32/warp), KV tile = 64 keys.
// S^T = mfma32(K, Q): lane owns q = lane&31 -> softmax fully per-lane +
// one shfl_xor(32).  O^T = mfma32(V^T, P^T): rescale lane-local.
// P^T B-frags are the lane's OWN e-values in natural order kappa(e,hi);
// V^T A-frag loaded in the SAME kappa order (k-permutation cancellation).
// This round: hint prefetched 1 iter ahead (latency hiding), tree max,
// defer-max (T13, THR=8 log2), setprio around MFMA clusters (T5).
__global__ __launch_bounds__(512) void k_attn2(
    const bf16_t* __restrict__ Qb, const bf16_t* __restrict__ Kb,
    const bf16_t* __restrict__ Vt, const float* __restrict__ hint,
    bf16_t* __restrict__ Ob) {
  __shared__ alignas(16) char sK[2][8192];   // [64 key][64 hd] swizzled
  __shared__ alignas(16) char sV[2][8192];   // [64 hd][64 key] swizzled
  __shared__ alignas(16) char sO[32768];     // per-warp 4KB: [32 q][64 hd]
  const int t = threadIdx.x, lane = t & 63, w = t >> 6;
  const int bh = blockIdx.x & 63, qc = blockIdx.x >> 6;  // bh fastest: same-bh
  const int b = bh >> 4, h = bh & 15;                    // blocks -> same XCD
  const int l31 = lane & 31, hi = lane >> 5;
  const int rs = (l31 & 7) << 4;

  // Q B-frags (held in registers, Q pre-scaled by CQK2f in GEMM1)
  bf16x8 qf[4];
  {
    const bf16_t* Qg =
        Qb + ((size_t)bh * SEQ + qc * 256 + w * 32 + l31) * HDIM + hi * 8;
#pragma unroll
    for (int kb = 0; kb < 4; kb++) qf[kb] = *(const bf16x8*)(Qg + kb * 16);
  }

  // staging: thread t covers row srow, 16B segment sseg (same for K and V^T)
  const int srow = t >> 3, sseg = t & 7;
  const bf16_t* Kg =
      Kb + (size_t)bh * SEQ * HDIM + (size_t)srow * HDIM + sseg * 8;
  const bf16_t* Vg =
      Vt + (size_t)bh * HDIM * SEQ + (size_t)srow * SEQ + sseg * 8;
  const int soff = srow * 128 + ((sseg * 16) ^ ((srow & 7) << 4));

  {  // prologue: stage tile 0
    u32x4 k0 = *(const u32x4*)Kg;
    u32x4 v0 = *(const u32x4*)Vg;
    *(u32x4*)(sK[0] + soff) = k0;
    *(u32x4*)(sV[0] + soff) = v0;
  }

  const float* hb = hint + b * SEQ + hi * 4;

  // hint prefetch registers: hc[g] g=0..3 -> s0 groups, g=4..7 -> s1 groups
  f32x4 hc[8];
#pragma unroll
  for (int g = 0; g < 8; g++)
    hc[g] = *(const f32x4*)(hb + ((g >> 2) << 5) + (g & 3) * 8);

  float m_run = -1e30f, l_run = 0.f;
  f32x16 oa0, oa1;
#pragma unroll
  for (int r = 0; r < 16; r++) { oa0[r] = 0.f; oa1[r] = 0.f; }

  for (int kt = 0; kt < 32; ++kt) {
    const int cur = kt & 1;
    u32x4 knx, vnx;
    if (kt < 31) {  // T14: issue next-tile loads before compute
      knx = *(const u32x4*)(Kg + (size_t)(kt + 1) * (KVB * HDIM));
      vnx = *(const u32x4*)(Vg + (kt + 1) * KVB);
    }
    __syncthreads();
    const char* bK = sK[cur];
    const char* bV = sV[cur];

    // S^T accumulators, init = hint[key]*LOG2E (prefetched last iter)
    f32x16 s0, s1;
#pragma unroll
    for (int g = 0; g < 4; g++)
#pragma unroll
      for (int j = 0; j < 4; j++) {
        s0[4 * g + j] = hc[g][j] * LOG2Ef;
        s1[4 * g + j] = hc[4 + g][j] * LOG2Ef;
      }
    // refill hint prefetch for next iter (full-iter latency distance)
    if (kt < 31) {
#pragma unroll
      for (int g = 0; g < 8; g++)
        hc[g] = *(const f32x4*)(hb + (kt + 1) * 64 + ((g >> 2) << 5) +
                                (g & 3) * 8);
    }

    // QK^T (swapped): A = K rows, B = Q  (same consecutive-k order both sides)
    __builtin_amdgcn_s_setprio(1);
#pragma unroll
    for (int kb = 0; kb < 4; kb++) {
      const int co = (kb * 32 + hi * 16) ^ rs;
      bf16x8 ka0 = *(const bf16x8*)(bK + l31 * 128 + co);
      bf16x8 ka1 = *(const bf16x8*)(bK + (32 + l31) * 128 + co);
      s0 = MFMA32(ka0, qf[kb], s0);
      s1 = MFMA32(ka1, qf[kb], s1);
    }
    __builtin_amdgcn_s_setprio(0);

    // online softmax: per-lane (one q-row), tree max + defer-max (THR=8)
    float m8[8];
#pragma unroll
    for (int r = 0; r < 8; r++)
      m8[r] = fmaxf(fmaxf(s0[r], s0[r + 8]), fmaxf(s1[r], s1[r + 8]));
    float pm = fmaxf(fmaxf(fmaxf(m8[0], m8[1]), fmaxf(m8[2], m8[3])),
                     fmaxf(fmaxf(m8[4], m8[5]), fmaxf(m8[6], m8[7])));
    pm = fmaxf(pm, __shfl_xor(pm, 32));
    if (__any(pm > m_run + 8.f)) {  // rescale only when max grew > 2^8
      const float mn = fmaxf(m_run, pm);
      const float corr = __builtin_amdgcn_exp2f(m_run - mn);
      m_run = mn;
      l_run *= corr;
#pragma unroll
      for (int r = 0; r < 16; r++) { oa0[r] *= corr; oa1[r] *= corr; }
    }
    const float mn = m_run;
    float e0[16], e1[16];
    float ps0 = 0.f, ps1 = 0.f, ps2 = 0.f, ps3 = 0.f;
#pragma unroll
    for (int r = 0; r < 16; r += 4) {
      e0[r + 0] = __builtin_amdgcn_exp2f(s0[r + 0] - mn); ps0 += e0[r + 0];
      e0[r + 1] = __builtin_amdgcn_exp2f(s0[r + 1] - mn); ps1 += e0[r + 1];
      e0[r + 2] = __builtin_amdgcn_exp2f(s0[r + 2] - mn); ps2 += e0[r + 2];
      e0[r + 3] = __builtin_amdgcn_exp2f(s0[r + 3] - mn); ps3 += e0[r + 3];
    }
#pragma unroll
    for (int r = 0; r < 16; r += 4) {
      e1[r + 0] = __builtin_amdgcn_exp2f(s1[r + 0] - mn); ps0 += e1[r + 0];
      e1[r + 1] = __builtin_amdgcn_exp2f(s1[r + 1] - mn); ps1 += e1[r + 1];
      e1[r + 2] = __builtin_amdgcn_exp2f(s1[r + 2] - mn); ps2 += e1[r + 2];
      e1[r + 3] = __builtin_amdgcn_exp2f(s1[r + 3] - mn); ps3 += e1[r + 3];
    }
    float ps = (ps0 + ps1) + (ps2 + ps3);
    ps += __shfl_xor(ps, 32);
    l_run += ps;

    // PV (swapped): O^T += V^T @ P^T.
    // B (P^T): lane's own e-values, natural order kappa(e,hi).
    // A (V^T): rows l31 / 32+l31, keys loaded in the SAME kappa order:
    //   elems 0-3 = keys KS*16+4*hi+0..3, elems 4-7 = keys KS*16+8+4*hi+0..3.
#define PVSTEP(EARR, KS)                                                      \
    {                                                                         \
      constexpr int rb = ((KS) & 1) * 8;                                      \
      u32x4 pw;                                                               \
      pw[0] = pk2(EARR[rb + 0], EARR[rb + 1]);                                \
      pw[1] = pk2(EARR[rb + 2], EARR[rb + 3]);                                \
      pw[2] = pk2(EARR[rb + 4], EARR[rb + 5]);                                \
      pw[3] = pk2(EARR[rb + 6], EARR[rb + 7]);                                \
      bf16x8 pf = __builtin_bit_cast(bf16x8, pw);                             \
      const int c0 = ((KS) * 32 + 8 * hi) ^ rs;                               \
      const int c1 = ((KS) * 32 + 16 + 8 * hi) ^ rs;                          \
      u32x2 a0l = *(const u32x2*)(bV + l31 * 128 + c0);                       \
      u32x2 a0h = *(const u32x2*)(bV + l31 * 128 + c1);                       \
      u32x2 a1l = *(const u32x2*)(bV + (32 + l31) * 128 + c0);                \
      u32x2 a1h = *(const u32x2*)(bV + (32 + l31) * 128 + c1);                \
      u32x4 w0; w0[0] = a0l[0]; w0[1] = a0l[1]; w0[2] = a0h[0]; w0[3] = a0h[1];\
      u32x4 w1; w1[0] = a1l[0]; w1[1] = a1l[1]; w1[2] = a1h[0]; w1[3] = a1h[1];\
      oa0 = MFMA32(__builtin_bit_cast(bf16x8, w0), pf, oa0);                  \
      oa1 = MFMA32(__builtin_bit_cast(bf16x8, w1), pf, oa1);                  \
    }
    __builtin_amdgcn_s_setprio(1);
    PVSTEP(e0, 0)
    PVSTEP(e0, 1)
    PVSTEP(e1, 2)
    PVSTEP(e1, 3)
    __builtin_amdgcn_s_setprio(0);
#undef PVSTEP

    if (kt < 31) {  // write next tile into other buffer
      *(u32x4*)(sK[cur ^ 1] + soff) = knx;
      *(u32x4*)(sV[cur ^ 1] + soff) = vnx;
    }
  }

  // epilogue: normalize, per-warp LDS transpose O^T -> O, vector store
  const float inv = __builtin_amdgcn_rcpf(l_run);
  char* so = sO + w * 4096;
#pragma unroll
  for (int g = 0; g < 4; g++) {
    {
      u32x2 wv;
      wv[0] = pk2(oa0[4 * g + 0] * inv, oa0[4 * g + 1] * inv);
      wv[1] = pk2(oa0[4 * g + 2] * inv, oa0[4 * g + 3] * inv);
      const int colb = 16 * g + 8 * hi;  // hd = 8g+4hi, bytes
      *(u32x2*)(so + l31 * 128 + (colb ^ rs)) = wv;
    }
    {
      u32x2 wv;
      wv[0] = pk2(oa1[4 * g + 0] * inv, oa1[4 * g + 1] * inv);
      wv[1] = pk2(oa1[4 * g + 2] * inv, oa1[4 * g + 3] * inv);
      const int colb = 64 + 16 * g + 8 * hi;
      *(u32x2*)(so + l31 * 128 + (colb ^ rs)) = wv;
    }
  }
  // readback rows (same warp produced them; compiler orders via lgkmcnt)
  const int row = lane >> 1, halfq = lane & 1;
  const int rs2 = (row & 7) << 4;
  bf16_t* od = Ob + ((size_t)b * SEQ + qc * 256 + w * 32 + row) * EMB +
               h * HDIM + halfq * 32;
#pragma unroll
  for (int s2 = 0; s2 < 4; s2++) {
    u32x4 d = *(const u32x4*)(so + row * 128 + ((halfq * 64 + s2 * 16) ^ rs2));
    *(u32x4*)(od + s2 * 8) = d;
  }
}

// ------------------------------- launcher ------------------------------------
extern "C" void kernel_launch(void* const* d_in, const int* in_sizes, int n_in,
                              void* d_out, int out_size, void* d_ws,
                              size_t ws_size, hipStream_t stream) {
  const float* x    = (const float*)d_in[0];
  const float* hint = (const float*)d_in[1];
  const float* Wq   = (const float*)d_in[2];
  const float* bq   = (const float*)d_in[3];
  const float* Wk   = (const float*)d_in[4];
  const float* bk   = (const float*)d_in[5];
  const float* Wv   = (const float*)d_in[6];
  const float* bv   = (const float*)d_in[7];
  const float* Wo   = (const float*)d_in[8];
  const float* bo   = (const float*)d_in[9];
  float* out = (float*)d_out;

  char* w = (char*)d_ws;
  const size_t MB = 1024 * 1024;
  bf16_t* xb    = (bf16_t*)(w);            // 16 MB
  bf16_t* wqkvt = (bf16_t*)(w + 16 * MB);  // 6 MB
  bf16_t* wot   = (bf16_t*)(w + 22 * MB);  // 2 MB
  bf16_t* qb    = (bf16_t*)(w + 24 * MB);  // 16 MB (B,H,N,64), pre-scaled
  bf16_t* kb    = (bf16_t*)(w + 40 * MB);  // 16 MB (B,H,N,64)
  bf16_t* vt    = (bf16_t*)(w + 56 * MB);  // 16 MB (B,H,64,N) transposed
  bf16_t* ob    = (bf16_t*)(w + 72 * MB);  // 16 MB (B,N,EMB)

  // prepass
  k_cvt_x<<<(MTOT * EMB) / 1024, 256, 0, stream>>>(x, xb);
  dim3 wtg(32, 32), wtb(32, 8);
  k_wt<<<wtg, wtb, 0, stream>>>(Wq, wqkvt);
  k_wt<<<wtg, wtb, 0, stream>>>(Wk, wqkvt + (size_t)EMB * EMB);
  k_wt<<<wtg, wtb, 0, stream>>>(Wv, wqkvt + (size_t)2 * EMB * EMB);
  k_wt<<<wtg, wtb, 0, stream>>>(Wo, wot);

  // QKV projection: (8192 x 3072) = xb @ [Wq|Wk|Wv]
  k_gemm<0><<<64 * 24, 256, 0, stream>>>(xb, wqkvt, 24, qb, kb, vt, bq, bk, bv,
                                         nullptr);
  // attention: 512 blocks (8 q-chunks x 64 bh), 512 threads
  k_attn2<<<512, 512, 0, stream>>>(qb, kb, vt, hint, ob);
  // output projection
  k_gemm<1><<<64 * 8, 256, 0, stream>>>(ob, wot, 8, nullptr, nullptr, nullptr,
                                        bo, nullptr, nullptr, out);
}